// Round 11
// baseline (451.366 us; speedup 1.0000x reference)
//
#include <hip/hip_runtime.h>

#define HSZ 32
#define SEQ 1024

typedef float v2f __attribute__((ext_vector_type(2)));

__device__ __forceinline__ float fast_rcp(float v) { return __builtin_amdgcn_rcpf(v); }

// sigmoid(x) = 1/(1+exp(-x)); exp args bounded (|g| <~ 10), rcp(inf)=0 saturation safe.
__device__ __forceinline__ float sigmoidf_(float v) {
    return fast_rcp(1.0f + __expf(-v));
}
__device__ __forceinline__ float tanhf_(float v) {
    return fmaf(2.0f, sigmoidf_(2.0f * v), -1.0f);
}

// r11: ONE batch per wave (2048 waves = 2/SIMD for chain interleave).
// Lanes u and u+32 BOTH own unit u's all-four gates, k-SPLIT: low half
// accumulates k<16 (plus x-proj+bias), high half k>=16. Four shfl_xor(32)
// combine the gate sums in both halves; nonlinearities run redundantly ->
// no gate exchange on the chain. Attention scored in-lane on h_{t-1} from
// the half-hp (r6-proven delayed accumulation) + one combine shuffle.
// DS ops/wave-step: 10 (r7: 14 at twice the weight regs).
__global__ __launch_bounds__(64)
__attribute__((amdgpu_waves_per_eu(2, 2)))
void lstm_attn_fused(const float* __restrict__ x,
                     const float* __restrict__ W_ih,
                     const float* __restrict__ W_hh,
                     const float* __restrict__ b_ih,
                     const float* __restrict__ b_hh,
                     const float* __restrict__ attn_w,
                     const float* __restrict__ fc1_w,
                     const float* __restrict__ fc1_b,
                     const float* __restrict__ fc2_w,
                     const float* __restrict__ fc2_b,
                     float* __restrict__ out)
{
    const int lane = threadIdx.x;        // 0..63
    const int u    = lane & 31;          // hidden unit owned by this lane
    const bool low = lane < 32;
    const int half = lane >> 5;          // k-half this lane accumulates
    const int b    = blockIdx.x;         // batch element
    const int j0   = half * 8;           // v2f offset into the k dimension

    // ---- weights: 4 gate rows x 8 v2f (this lane's k-half) ----
    const v2f* __restrict__ Whv = (const v2f*)W_hh;      // [128][16] v2f
    const v2f* __restrict__ awp = (const v2f*)attn_w;    // [16] v2f
    v2f wI[8], wF[8], wG[8], wO[8], awv[8];
#pragma unroll
    for (int j = 0; j < 8; ++j) {
        wI[j]  = Whv[(u      ) * 16 + j0 + j];
        wF[j]  = Whv[(u + 32 ) * 16 + j0 + j];
        wG[j]  = Whv[(u + 64 ) * 16 + j0 + j];
        wO[j]  = Whv[(u + 96 ) * 16 + j0 + j];
        awv[j] = awp[j0 + j];
    }
    // x-projection + bias contribute to the LOW partial only (high inits 0)
    float wiI[3], wiF[3], wiG[3], wiO[3];
#pragma unroll
    for (int j = 0; j < 3; ++j) {
        wiI[j] = low ? W_ih[(u      ) * 3 + j] : 0.0f;
        wiF[j] = low ? W_ih[(u + 32 ) * 3 + j] : 0.0f;
        wiG[j] = low ? W_ih[(u + 64 ) * 3 + j] : 0.0f;
        wiO[j] = low ? W_ih[(u + 96 ) * 3 + j] : 0.0f;
    }
    float bI = low ? (b_ih[u     ] + b_hh[u     ]) : 0.0f;
    float bF = low ? (b_ih[u + 32] + b_hh[u + 32]) : 0.0f;
    float bG = low ? (b_ih[u + 64] + b_hh[u + 64]) : 0.0f;
    float bO = low ? (b_ih[u + 96] + b_hh[u + 96]) : 0.0f;

    // Pin loop-invariants (asm defs can't be rematerialized from memory).
#pragma unroll
    for (int j = 0; j < 8; ++j) {
        asm volatile("" : "+v"(wI[j]), "+v"(wF[j]), "+v"(wG[j]), "+v"(wO[j]), "+v"(awv[j]));
    }
#pragma unroll
    for (int j = 0; j < 3; ++j) {
        asm volatile("" : "+v"(wiI[j]), "+v"(wiF[j]), "+v"(wiG[j]), "+v"(wiO[j]));
    }
    asm volatile("" : "+v"(bI), "+v"(bF), "+v"(bG), "+v"(bO));

    // h state: hbuf[0..31] authoritative (written by low lanes).
    __shared__ float hbuf[64];
    hbuf[lane] = 0.0f;
    const v2f* __restrict__ hb2 = (const v2f*)hbuf + j0;  // this lane's k-half

    float c = 0.0f, h = 0.0f;
    float Pacc = 0.0f, lacc = 0.0f;      // online softmax pooling (scores bounded ~5.7)

    const float4* __restrict__ xv = (const float4*)(x + (size_t)b * SEQ * 3);

    // hp holds this lane's k-half of h_{t-1}; h0 = 0.
    v2f hp[8];
#pragma unroll
    for (int j = 0; j < 8; ++j) { hp[j].x = 0.0f; hp[j].y = 0.0f; }

    auto step = [&](float x0, float x1, float x2, float accum) {
        // ---- attention on h_{t-1} (from hp; this lane's h reg still = h_{t-1}) ----
        v2f apv = {0.0f, 0.0f};
#pragma unroll
        for (int j = 0; j < 8; ++j) apv = __builtin_elementwise_fma(awv[j], hp[j], apv);
        float ps = apv.x + apv.y;
        const float p = ps + __shfl_xor(ps, 32);           // full dot over 32 units
        const float wgt = accum * __expf(fmaxf(p, 0.0f));
        lacc += wgt;
        Pacc = fmaf(wgt, h, Pacc);

        // ---- gate partials over this lane's k-half ----
        v2f aI; aI.x = fmaf(wiI[0],x0, fmaf(wiI[1],x1, fmaf(wiI[2],x2, bI))); aI.y = 0.0f;
        v2f aF; aF.x = fmaf(wiF[0],x0, fmaf(wiF[1],x1, fmaf(wiF[2],x2, bF))); aF.y = 0.0f;
        v2f aG; aG.x = fmaf(wiG[0],x0, fmaf(wiG[1],x1, fmaf(wiG[2],x2, bG))); aG.y = 0.0f;
        v2f aO; aO.x = fmaf(wiO[0],x0, fmaf(wiO[1],x1, fmaf(wiO[2],x2, bO))); aO.y = 0.0f;
#pragma unroll
        for (int j = 0; j < 8; ++j) {
            aI = __builtin_elementwise_fma(wI[j], hp[j], aI);
            aF = __builtin_elementwise_fma(wF[j], hp[j], aF);
            aG = __builtin_elementwise_fma(wG[j], hp[j], aG);
            aO = __builtin_elementwise_fma(wO[j], hp[j], aO);
        }
        float pI = aI.x + aI.y, pF = aF.x + aF.y;
        float pG = aG.x + aG.y, pO = aO.x + aO.y;

        // combine k-halves: both lanes of the pair get the full sums
        const float sI = pI + __shfl_xor(pI, 32);
        const float sF = pF + __shfl_xor(pF, 32);
        const float sG = pG + __shfl_xor(pG, 32);
        const float sO = pO + __shfl_xor(pO, 32);

        // nonlinearities (redundant in the pair -- no exchange on chain)
        const float i_ = sigmoidf_(sI);
        const float f_ = sigmoidf_(sF);
        const float g_ = tanhf_   (sG);
        const float o_ = sigmoidf_(sO);

        c = fmaf(f_, c, i_ * g_);
        h = o_ * tanhf_(c);              // identical in lanes u and u+32

        hbuf[lane] = h;                  // slots 0..31 (low lanes) are the state

        // prefetch this lane's k-half of h_t (in-order DS: reads see the write)
#pragma unroll
        for (int j = 0; j < 8; ++j) hp[j] = hb2[j];
    };

    // x software pipeline: prefetch next 4-step group while computing current
    float4 xa = xv[0], xb = xv[1], xc = xv[2];
    for (int s0 = 0; s0 < SEQ; s0 += 4) {
        const int nfi = ((s0 + 4) < SEQ) ? (((s0 + 4) * 3) >> 2) : 0;
        const float4 na = xv[nfi], nb = xv[nfi + 1], nc = xv[nfi + 2];
        step(xa.x, xa.y, xa.z, (s0 == 0) ? 0.0f : 1.0f);   // mask phantom h0 score
        step(xa.w, xb.x, xb.y, 1.0f);
        step(xb.z, xb.w, xc.x, 1.0f);
        step(xc.y, xc.z, xc.w, 1.0f);
        xa = na; xb = nb; xc = nc;
    }
    // tail: score the final h (hp = h_SEQ after the last prefetch)
    {
        v2f apv = {0.0f, 0.0f};
#pragma unroll
        for (int j = 0; j < 8; ++j) apv = __builtin_elementwise_fma(awv[j], hp[j], apv);
        float ps = apv.x + apv.y;
        const float p = ps + __shfl_xor(ps, 32);
        const float wgt = __expf(fmaxf(p, 0.0f));
        lacc += wgt;
        Pacc = fmaf(wgt, h, Pacc);
    }

    // ---- epilogue: pooled -> fc1(relu) -> fc2 (single-wave, no barriers) ----
    hbuf[lane] = Pacc * fast_rcp(lacc);  // pooled[u] in slots 0..31

    {
        const int j = lane & 15;         // fc1 row (computed redundantly by 4 lanes)
        float acc = fc1_b[j];
#pragma unroll
        for (int k = 0; k < HSZ; ++k)
            acc = fmaf(fc1_w[j * HSZ + k], hbuf[k], acc);
        __shared__ float h1sh[16];
        if (lane < 16) h1sh[j] = fmaxf(acc, 0.0f);

        if (lane < 2) {
            float acc2 = fc2_b[lane];
#pragma unroll
            for (int m = 0; m < 16; ++m)
                acc2 = fmaf(fc2_w[lane * 16 + m], h1sh[m], acc2);
            out[b * 2 + lane] = acc2;
        }
    }
}

extern "C" void kernel_launch(void* const* d_in, const int* in_sizes, int n_in,
                              void* d_out, int out_size, void* d_ws, size_t ws_size,
                              hipStream_t stream) {
    const float* x      = (const float*)d_in[0];
    const float* W_ih   = (const float*)d_in[1];
    const float* W_hh   = (const float*)d_in[2];
    const float* b_ih   = (const float*)d_in[3];
    const float* b_hh   = (const float*)d_in[4];
    const float* attn_w = (const float*)d_in[5];
    const float* fc1_w  = (const float*)d_in[6];
    const float* fc1_b  = (const float*)d_in[7];
    const float* fc2_w  = (const float*)d_in[8];
    const float* fc2_b  = (const float*)d_in[9];

    const int B = in_sizes[0] / (SEQ * 3);   // 2048

    lstm_attn_fused<<<dim3(B), dim3(64), 0, stream>>>(
        x, W_ih, W_hh, b_ih, b_hh, attn_w, fc1_w, fc1_b, fc2_w, fc2_b,
        (float*)d_out);
}